// Round 2
// baseline (1276.510 us; speedup 1.0000x reference)
//
#include <hip/hip_runtime.h>
#include <hip/hip_bf16.h>

#define NEG_SLOPE 0.2f

// h = X @ W ; as[n] = h[n]·a_src ; ad[n] = h[n]·a_dst
// One wave per row: lane l computes h[row][l]; W staged in LDS.
template<int K>
__global__ __launch_bounds__(256) void gemm_alpha_kernel(
    const float* __restrict__ X, const float* __restrict__ W,
    const float* __restrict__ a_src, const float* __restrict__ a_dst,
    float* __restrict__ h, float* __restrict__ as_, float* __restrict__ ad_, int N)
{
    __shared__ float Ws[K * 64];
    __shared__ float Xs[4 * K];
    const int t = threadIdx.x;
    for (int i = t; i < K * 64; i += 256) Ws[i] = W[i];
    const int row0 = blockIdx.x * 4;
    for (int i = t; i < 4 * K; i += 256) {
        int r = row0 + i / K;
        Xs[i] = (r < N) ? X[(size_t)r * K + (i % K)] : 0.f;
    }
    __syncthreads();
    const int wave = t >> 6, lane = t & 63;
    const int row = row0 + wave;
    if (row >= N) return;
    const float* xr = &Xs[wave * K];
    float acc = 0.f;
#pragma unroll 8
    for (int k = 0; k < K; ++k) acc += xr[k] * Ws[k * 64 + lane];
    h[(size_t)row * 64 + lane] = acc;
    float va = acc * a_src[lane];
    float vd = acc * a_dst[lane];
#pragma unroll
    for (int off = 32; off > 0; off >>= 1) {
        va += __shfl_down(va, off, 64);
        vd += __shfl_down(vd, off, 64);
    }
    if (lane == 0) { as_[row] = va; ad_[row] = vd; }
}

// s[dst] += exp(leaky_relu(as[src]+ad[dst]))   (one thread per edge; self-loops appended)
__global__ __launch_bounds__(256) void edge_sumexp_kernel(
    const int* __restrict__ adj, const float* __restrict__ as_,
    const float* __restrict__ ad_, float* __restrict__ s, int E, int N)
{
    int e = blockIdx.x * blockDim.x + threadIdx.x;
    if (e >= E + N) return;
    int sN, dN;
    if (e < E) { sN = adj[e]; dN = adj[E + e]; } else { sN = dN = e - E; }
    float x = as_[sN] + ad_[dN];
    x = x > 0.f ? x : NEG_SLOPE * x;
    atomicAdd(&s[dN], __expf(x));
}

// acc[dst][j] += exp(e) * h[src][j]   (one wave per edge, lane j = feature j)
__global__ __launch_bounds__(256) void edge_aggregate_kernel(
    const int* __restrict__ adj, const float* __restrict__ as_, const float* __restrict__ ad_,
    const float* __restrict__ h, float* __restrict__ acc, int E, int N)
{
    long long gid = (long long)blockIdx.x * blockDim.x + threadIdx.x;
    int e = (int)(gid >> 6);
    int lane = threadIdx.x & 63;
    if (e >= E + N) return;
    int sN, dN;
    if (e < E) { sN = adj[e]; dN = adj[E + e]; } else { sN = dN = e - E; }
    float x = as_[sN] + ad_[dN];
    x = x > 0.f ? x : NEG_SLOPE * x;
    float p = __expf(x);
    float v = h[(size_t)sN * 64 + lane];
    atomicAdd(&acc[(size_t)dN * 64 + lane], p * v);
}

// x[n][j] = act(acc[n][j] / s[n] + b[j])  in place
__global__ __launch_bounds__(256) void finalize_kernel(
    float* __restrict__ acc, const float* __restrict__ s,
    const float* __restrict__ b, int N, int do_elu)
{
    int i = blockIdx.x * blockDim.x + threadIdx.x;
    if (i >= N * 64) return;
    int n = i >> 6, j = i & 63;
    float v = acc[i] / s[n] + b[j];
    if (do_elu) v = v > 0.f ? v : (__expf(v) - 1.f);
    acc[i] = v;
}

// logits[n][c] = x[n]·cW[:,c] + cb[c]
__global__ __launch_bounds__(256) void classifier_kernel(
    const float* __restrict__ x, const float* __restrict__ cw,
    const float* __restrict__ cb, float* __restrict__ out, int N)
{
    int i = blockIdx.x * blockDim.x + threadIdx.x;
    if (i >= N * 16) return;
    int n = i >> 4, c = i & 15;
    const float* xr = x + (size_t)n * 64;
    float acc = cb[c];
#pragma unroll
    for (int j = 0; j < 64; ++j) acc += xr[j] * cw[j * 16 + c];
    out[i] = acc;
}

__global__ __launch_bounds__(256) void copy_out_kernel(
    const float* __restrict__ x, float* __restrict__ out, int n)
{
    int i = blockIdx.x * blockDim.x + threadIdx.x;
    if (i < n) out[i] = x[i];
}

extern "C" void kernel_launch(void* const* d_in, const int* in_sizes, int n_in,
                              void* d_out, int out_size, void* d_ws, size_t ws_size,
                              hipStream_t stream)
{
    const float* X    = (const float*)d_in[0];
    const int*   adj  = (const int*)d_in[1];
    const float* W1   = (const float*)d_in[2];
    const float* a_s1 = (const float*)d_in[3];
    const float* a_d1 = (const float*)d_in[4];
    const float* b1   = (const float*)d_in[5];
    const float* W2   = (const float*)d_in[6];
    const float* a_s2 = (const float*)d_in[7];
    const float* a_d2 = (const float*)d_in[8];
    const float* b2   = (const float*)d_in[9];
    const float* cW   = (const float*)d_in[10];
    const float* cb   = (const float*)d_in[11];

    const int N = in_sizes[0] / 128;
    const int E = in_sizes[1] / 2;
    const int ET = E + N;

    float* A   = (float*)d_ws;              // h buffer, N*64
    float* B   = A + (size_t)N * 64;        // acc/x buffer, N*64
    float* asb = B + (size_t)N * 64;        // N
    float* adb = asb + N;                   // N
    float* sb  = adb + N;                   // N

    const int threads = 256;
    const int gemmBlocks = (N + 3) / 4;
    const int edgeBlocks = (ET + threads - 1) / threads;
    const long long aggT = (long long)ET * 64;
    const int aggBlocks = (int)((aggT + threads - 1) / threads);
    const int nodeFeatBlocks = (N * 64 + threads - 1) / threads;

    // ---------- layer 1 ----------
    hipMemsetAsync(B, 0, (size_t)N * 64 * sizeof(float), stream);
    hipMemsetAsync(sb, 0, (size_t)N * sizeof(float), stream);
    gemm_alpha_kernel<128><<<gemmBlocks, threads, 0, stream>>>(
        X, W1, a_s1, a_d1, A, asb, adb, N);
    edge_sumexp_kernel<<<edgeBlocks, threads, 0, stream>>>(adj, asb, adb, sb, E, N);
    edge_aggregate_kernel<<<aggBlocks, threads, 0, stream>>>(adj, asb, adb, A, B, E, N);
    finalize_kernel<<<nodeFeatBlocks, threads, 0, stream>>>(B, sb, b1, N, 1);

    // ---------- layer 2 ----------
    gemm_alpha_kernel<64><<<gemmBlocks, threads, 0, stream>>>(
        B, W2, a_s2, a_d2, A, asb, adb, N);
    hipMemsetAsync(B, 0, (size_t)N * 64 * sizeof(float), stream);
    hipMemsetAsync(sb, 0, (size_t)N * sizeof(float), stream);
    edge_sumexp_kernel<<<edgeBlocks, threads, 0, stream>>>(adj, asb, adb, sb, E, N);
    edge_aggregate_kernel<<<aggBlocks, threads, 0, stream>>>(adj, asb, adb, A, B, E, N);
    finalize_kernel<<<nodeFeatBlocks, threads, 0, stream>>>(B, sb, b2, N, 0);

    // ---------- classifier + outputs ----------
    float* out = (float*)d_out;
    classifier_kernel<<<(N * 16 + threads - 1) / threads, threads, 0, stream>>>(
        B, cW, cb, out, N);
    copy_out_kernel<<<nodeFeatBlocks, threads, 0, stream>>>(
        B, out + (size_t)N * 16, N * 64);
}

// Round 3
// 832.123 us; speedup vs baseline: 1.5340x; 1.5340x over previous
//
#include <hip/hip_runtime.h>
#include <hip/hip_bf16.h>

#define NEG_SLOPE 0.2f

// ---------------- CSR build (counting sort by dst) ----------------

__global__ __launch_bounds__(256) void init_deg_kernel(int* __restrict__ deg, int N)
{
    int i = blockIdx.x * blockDim.x + threadIdx.x;
    if (i < N) deg[i] = 1;  // self-loop
}

__global__ __launch_bounds__(256) void count_deg_kernel(
    const int* __restrict__ adj, int* __restrict__ deg, int E)
{
    int e = blockIdx.x * blockDim.x + threadIdx.x;
    if (e < E) atomicAdd(&deg[adj[E + e]], 1);
}

// per-1024-block inclusive scan; row_ptr[i+1] = local inclusive, bsum[b] = block total
__global__ __launch_bounds__(1024) void scan1_kernel(
    const int* __restrict__ deg, int* __restrict__ row_ptr, int* __restrict__ bsum, int N)
{
    __shared__ int s[1024];
    int i = blockIdx.x * 1024 + threadIdx.x;
    int v = (i < N) ? deg[i] : 0;
    s[threadIdx.x] = v;
    __syncthreads();
    for (int off = 1; off < 1024; off <<= 1) {
        int t = (threadIdx.x >= off) ? s[threadIdx.x - off] : 0;
        __syncthreads();
        s[threadIdx.x] += t;
        __syncthreads();
    }
    if (i < N) row_ptr[i + 1] = s[threadIdx.x];
    if (threadIdx.x == 1023) bsum[blockIdx.x] = s[1023];
}

// exclusive scan of block sums (NB <= 1024)
__global__ __launch_bounds__(1024) void scan2_kernel(int* __restrict__ bsum, int NB)
{
    __shared__ int s[1024];
    int t = threadIdx.x;
    int v = (t < NB) ? bsum[t] : 0;
    s[t] = v;
    __syncthreads();
    for (int off = 1; off < 1024; off <<= 1) {
        int u = (t >= off) ? s[t - off] : 0;
        __syncthreads();
        s[t] += u;
        __syncthreads();
    }
    if (t < NB) bsum[t] = s[t] - v;
}

// apply block offsets; cursor[i] = exclusive scan = row start
__global__ __launch_bounds__(256) void scan3_kernel(
    int* __restrict__ row_ptr, int* __restrict__ cursor,
    const int* __restrict__ deg, const int* __restrict__ bsum, int N)
{
    int i = blockIdx.x * blockDim.x + threadIdx.x;
    if (i >= N) return;
    int r = row_ptr[i + 1] + bsum[i >> 10];
    row_ptr[i + 1] = r;
    cursor[i] = r - deg[i];
    if (i == 0) row_ptr[0] = 0;
}

__global__ __launch_bounds__(256) void scatter_kernel(
    const int* __restrict__ adj, int* __restrict__ cursor,
    int* __restrict__ col_idx, int E, int N)
{
    int e = blockIdx.x * blockDim.x + threadIdx.x;
    if (e >= E + N) return;
    int s, d;
    if (e < E) { s = adj[e]; d = adj[E + e]; } else { s = d = e - E; }
    int pos = atomicAdd(&cursor[d], 1);
    col_idx[pos] = s;
}

// ---------------- dense pieces ----------------

// h = X @ W ; as[n] = h[n]·a_src ; ad[n] = h[n]·a_dst   (one wave per row)
template<int K>
__global__ __launch_bounds__(256) void gemm_alpha_kernel(
    const float* __restrict__ X, const float* __restrict__ W,
    const float* __restrict__ a_src, const float* __restrict__ a_dst,
    float* __restrict__ h, float* __restrict__ as_, float* __restrict__ ad_, int N)
{
    __shared__ float Ws[K * 64];
    __shared__ float Xs[4 * K];
    const int t = threadIdx.x;
    for (int i = t; i < K * 64; i += 256) Ws[i] = W[i];
    const int row0 = blockIdx.x * 4;
    for (int i = t; i < 4 * K; i += 256) {
        int r = row0 + i / K;
        Xs[i] = (r < N) ? X[(size_t)r * K + (i % K)] : 0.f;
    }
    __syncthreads();
    const int wave = t >> 6, lane = t & 63;
    const int row = row0 + wave;
    if (row >= N) return;
    const float* xr = &Xs[wave * K];
    float acc = 0.f;
#pragma unroll 8
    for (int k = 0; k < K; ++k) acc += xr[k] * Ws[k * 64 + lane];
    h[(size_t)row * 64 + lane] = acc;
    float va = acc * a_src[lane];
    float vd = acc * a_dst[lane];
#pragma unroll
    for (int off = 32; off > 0; off >>= 1) {
        va += __shfl_down(va, off, 64);
        vd += __shfl_down(vd, off, 64);
    }
    if (lane == 0) { as_[row] = va; ad_[row] = vd; }
}

// Fused per-dst softmax + weighted aggregation + bias + activation.
// One wave per dst node; lane j = feature j. psum identical across lanes.
__global__ __launch_bounds__(256) void gat_aggregate_kernel(
    const int* __restrict__ row_ptr, const int* __restrict__ col_idx,
    const float* __restrict__ as_, const float* __restrict__ ad_,
    const float* __restrict__ h, const float* __restrict__ b,
    float* __restrict__ out, int N, int do_elu)
{
    int node = blockIdx.x * 4 + (threadIdx.x >> 6);
    int lane = threadIdx.x & 63;
    if (node >= N) return;
    int beg = row_ptr[node], end = row_ptr[node + 1];
    float ad = ad_[node];
    float acc = 0.f, psum = 0.f;
    for (int i = beg; i < end; ++i) {
        int s = col_idx[i];
        float x = as_[s] + ad;
        x = x > 0.f ? x : NEG_SLOPE * x;
        float p = __expf(x);
        psum += p;
        acc += p * h[(size_t)s * 64 + lane];
    }
    float v = acc / psum + b[lane];
    if (do_elu) v = v > 0.f ? v : (__expf(v) - 1.f);
    out[(size_t)node * 64 + lane] = v;
}

// logits[n][c] = x[n]·cW[:,c] + cb[c]
__global__ __launch_bounds__(256) void classifier_kernel(
    const float* __restrict__ x, const float* __restrict__ cw,
    const float* __restrict__ cb, float* __restrict__ out, int N)
{
    int i = blockIdx.x * blockDim.x + threadIdx.x;
    if (i >= N * 16) return;
    int n = i >> 4, c = i & 15;
    const float* xr = x + (size_t)n * 64;
    float acc = cb[c];
#pragma unroll
    for (int j = 0; j < 64; ++j) acc += xr[j] * cw[j * 16 + c];
    out[i] = acc;
}

extern "C" void kernel_launch(void* const* d_in, const int* in_sizes, int n_in,
                              void* d_out, int out_size, void* d_ws, size_t ws_size,
                              hipStream_t stream)
{
    const float* X    = (const float*)d_in[0];
    const int*   adj  = (const int*)d_in[1];
    const float* W1   = (const float*)d_in[2];
    const float* a_s1 = (const float*)d_in[3];
    const float* a_d1 = (const float*)d_in[4];
    const float* b1   = (const float*)d_in[5];
    const float* W2   = (const float*)d_in[6];
    const float* a_s2 = (const float*)d_in[7];
    const float* a_d2 = (const float*)d_in[8];
    const float* b2   = (const float*)d_in[9];
    const float* cW   = (const float*)d_in[10];
    const float* cb   = (const float*)d_in[11];

    const int N  = in_sizes[0] / 128;
    const int E  = in_sizes[1] / 2;
    const int ET = E + N;
    const int NB = (N + 1023) / 1024;

    // workspace layout (~60 MB)
    float* A       = (float*)d_ws;            // h,        N*64
    float* B       = A + (size_t)N * 64;      // layer1 x, N*64
    float* asb     = B + (size_t)N * 64;      // N
    float* adb     = asb + N;                 // N
    int*   deg     = (int*)(adb + N);         // N
    int*   cursor  = deg + N;                 // N
    int*   row_ptr = cursor + N;              // N+1
    int*   col_idx = row_ptr + (N + 1);       // E+N
    int*   bsum    = col_idx + ET;            // NB (<=1024)

    const int T = 256;
    const int nodeBlocks  = (N + T - 1) / T;
    const int edgeBlocksE = (E + T - 1) / T;
    const int edgeBlocksT = (ET + T - 1) / T;
    const int gemmBlocks  = (N + 3) / 4;
    const int aggBlocks   = (N + 3) / 4;

    // ---- CSR build (once, reused by both layers) ----
    init_deg_kernel<<<nodeBlocks, T, 0, stream>>>(deg, N);
    count_deg_kernel<<<edgeBlocksE, T, 0, stream>>>(adj, deg, E);
    scan1_kernel<<<NB, 1024, 0, stream>>>(deg, row_ptr, bsum, N);
    scan2_kernel<<<1, 1024, 0, stream>>>(bsum, NB);
    scan3_kernel<<<nodeBlocks, T, 0, stream>>>(row_ptr, cursor, deg, bsum, N);
    scatter_kernel<<<edgeBlocksT, T, 0, stream>>>(adj, cursor, col_idx, E, N);

    // ---- layer 1 ----
    gemm_alpha_kernel<128><<<gemmBlocks, T, 0, stream>>>(
        X, W1, a_s1, a_d1, A, asb, adb, N);
    gat_aggregate_kernel<<<aggBlocks, T, 0, stream>>>(
        row_ptr, col_idx, asb, adb, A, b1, B, N, 1);

    // ---- layer 2 (x written straight into d_out tail) ----
    float* out  = (float*)d_out;
    float* xout = out + (size_t)N * 16;
    gemm_alpha_kernel<64><<<gemmBlocks, T, 0, stream>>>(
        B, W2, a_s2, a_d2, A, asb, adb, N);
    gat_aggregate_kernel<<<aggBlocks, T, 0, stream>>>(
        row_ptr, col_idx, asb, adb, A, b2, xout, N, 0);

    // ---- classifier ----
    classifier_kernel<<<(N * 16 + T - 1) / T, T, 0, stream>>>(
        xout, cW, cb, out, N);
}

// Round 4
// 599.292 us; speedup vs baseline: 2.1300x; 1.3885x over previous
//
#include <hip/hip_runtime.h>
#include <hip/hip_bf16.h>

#define NEG_SLOPE 0.2f

// ---------------- CSR build (counting sort by dst) ----------------

__global__ __launch_bounds__(256) void init_deg_kernel(int* __restrict__ deg, int N)
{
    int i = blockIdx.x * blockDim.x + threadIdx.x;
    if (i < N) deg[i] = 1;  // self-loop
}

__global__ __launch_bounds__(256) void count_deg_kernel(
    const int* __restrict__ adj, int* __restrict__ deg, int E)
{
    int e = blockIdx.x * blockDim.x + threadIdx.x;
    if (e < E) atomicAdd(&deg[adj[E + e]], 1);
}

__global__ __launch_bounds__(1024) void scan1_kernel(
    const int* __restrict__ deg, int* __restrict__ row_ptr, int* __restrict__ bsum, int N)
{
    __shared__ int s[1024];
    int i = blockIdx.x * 1024 + threadIdx.x;
    int v = (i < N) ? deg[i] : 0;
    s[threadIdx.x] = v;
    __syncthreads();
    for (int off = 1; off < 1024; off <<= 1) {
        int t = (threadIdx.x >= off) ? s[threadIdx.x - off] : 0;
        __syncthreads();
        s[threadIdx.x] += t;
        __syncthreads();
    }
    if (i < N) row_ptr[i + 1] = s[threadIdx.x];
    if (threadIdx.x == 1023) bsum[blockIdx.x] = s[1023];
}

__global__ __launch_bounds__(1024) void scan2_kernel(int* __restrict__ bsum, int NB)
{
    __shared__ int s[1024];
    int t = threadIdx.x;
    int v = (t < NB) ? bsum[t] : 0;
    s[t] = v;
    __syncthreads();
    for (int off = 1; off < 1024; off <<= 1) {
        int u = (t >= off) ? s[t - off] : 0;
        __syncthreads();
        s[t] += u;
        __syncthreads();
    }
    if (t < NB) bsum[t] = s[t] - v;
}

__global__ __launch_bounds__(256) void scan3_kernel(
    int* __restrict__ row_ptr, int* __restrict__ cursor,
    const int* __restrict__ deg, const int* __restrict__ bsum, int N)
{
    int i = blockIdx.x * blockDim.x + threadIdx.x;
    if (i >= N) return;
    int r = row_ptr[i + 1] + bsum[i >> 10];
    row_ptr[i + 1] = r;
    cursor[i] = r - deg[i];
    if (i == 0) row_ptr[0] = 0;
}

__global__ __launch_bounds__(256) void scatter_kernel(
    const int* __restrict__ adj, int* __restrict__ cursor,
    int* __restrict__ col_idx, int E, int N)
{
    int e = blockIdx.x * blockDim.x + threadIdx.x;
    if (e >= E + N) return;
    int s, d;
    if (e < E) { s = adj[e]; d = adj[E + e]; } else { s = d = e - E; }
    int pos = atomicAdd(&cursor[d], 1);
    col_idx[pos] = s;
}

// ---------------- dense pieces ----------------

// h = X @ W ; as[n]=h·a_src ; ad[n]=h·a_dst. 32 rows/block, 8 rows/wave.
template<int K>
__global__ __launch_bounds__(256) void gemm_alpha_kernel(
    const float* __restrict__ X, const float* __restrict__ W,
    const float* __restrict__ a_src, const float* __restrict__ a_dst,
    float* __restrict__ h, float* __restrict__ as_, float* __restrict__ ad_, int N)
{
    __shared__ float Ws[K * 64];
    __shared__ float Xs[32 * K];
    const int t = threadIdx.x;
    for (int i = t * 4; i < K * 64; i += 1024)
        *(float4*)(Ws + i) = *(const float4*)(W + i);
    const int row0 = blockIdx.x * 32;
    for (int i = t * 4; i < 32 * K; i += 1024) {
        int r = row0 + i / K;
        float4 v = make_float4(0.f, 0.f, 0.f, 0.f);
        if (r < N) v = *(const float4*)(X + (size_t)r * K + (i % K));
        *(float4*)(Xs + i) = v;
    }
    __syncthreads();
    const int wave = t >> 6, lane = t & 63;
    const float a_s = a_src[lane], a_d = a_dst[lane];
    for (int rr = 0; rr < 8; ++rr) {
        int row = row0 + wave * 8 + rr;
        if (row >= N) break;
        const float* xr = &Xs[(wave * 8 + rr) * K];
        float acc = 0.f;
#pragma unroll
        for (int k4 = 0; k4 < K; k4 += 4) {
            float4 xv = *(const float4*)(xr + k4);
            acc += xv.x * Ws[(k4 + 0) * 64 + lane];
            acc += xv.y * Ws[(k4 + 1) * 64 + lane];
            acc += xv.z * Ws[(k4 + 2) * 64 + lane];
            acc += xv.w * Ws[(k4 + 3) * 64 + lane];
        }
        h[(size_t)row * 64 + lane] = acc;
        float va = acc * a_s, vd = acc * a_d;
#pragma unroll
        for (int off = 32; off > 0; off >>= 1) {
            va += __shfl_down(va, off, 64);
            vd += __shfl_down(vd, off, 64);
        }
        if (lane == 0) { as_[row] = va; ad_[row] = vd; }
    }
}

// Fused softmax+aggregate: one wave per dst node, 4 edges per wave-step,
// 16 lanes per edge (float4 over the 64-dim row), 2-deep unroll = 8 rows in flight.
__global__ __launch_bounds__(256) void gat_aggregate_kernel(
    const int* __restrict__ row_ptr, const int* __restrict__ col_idx,
    const float* __restrict__ as_, const float* __restrict__ ad_,
    const float* __restrict__ h, const float* __restrict__ b,
    float* __restrict__ out, int N, int do_elu)
{
    int node = blockIdx.x * 4 + (threadIdx.x >> 6);
    int lane = threadIdx.x & 63;
    int sub = lane >> 4, q = lane & 15;
    if (node >= N) return;
    int beg = row_ptr[node], end = row_ptr[node + 1];
    float ad = ad_[node];
    float4 acc = make_float4(0.f, 0.f, 0.f, 0.f);
    float psum = 0.f;
    for (int i = beg; i < end; i += 8) {
        int e0 = i + sub, e1 = i + 4 + sub;
        bool v0 = e0 < end, v1 = e1 < end;
        int s0 = col_idx[v0 ? e0 : end - 1];
        int s1 = col_idx[v1 ? e1 : end - 1];
        float x0 = as_[s0] + ad, x1 = as_[s1] + ad;
        const float4* h0 = (const float4*)(h + (size_t)s0 * 64) + q;
        const float4* h1 = (const float4*)(h + (size_t)s1 * 64) + q;
        float4 f0 = *h0;
        float4 f1 = *h1;
        x0 = x0 > 0.f ? x0 : NEG_SLOPE * x0;
        x1 = x1 > 0.f ? x1 : NEG_SLOPE * x1;
        float p0 = v0 ? __expf(x0) : 0.f;
        float p1 = v1 ? __expf(x1) : 0.f;
        psum += p0 + p1;
        acc.x += p0 * f0.x + p1 * f1.x;
        acc.y += p0 * f0.y + p1 * f1.y;
        acc.z += p0 * f0.z + p1 * f1.z;
        acc.w += p0 * f0.w + p1 * f1.w;
    }
    // reduce across the 4 sub-groups (lanes differing in bits 4,5)
#pragma unroll
    for (int off = 16; off <= 32; off <<= 1) {
        acc.x += __shfl_xor(acc.x, off, 64);
        acc.y += __shfl_xor(acc.y, off, 64);
        acc.z += __shfl_xor(acc.z, off, 64);
        acc.w += __shfl_xor(acc.w, off, 64);
        psum  += __shfl_xor(psum,  off, 64);
    }
    if (sub == 0) {
        float inv = 1.f / psum;
        float4 bb = ((const float4*)b)[q];
        float4 v;
        v.x = acc.x * inv + bb.x;
        v.y = acc.y * inv + bb.y;
        v.z = acc.z * inv + bb.z;
        v.w = acc.w * inv + bb.w;
        if (do_elu) {
            v.x = v.x > 0.f ? v.x : (__expf(v.x) - 1.f);
            v.y = v.y > 0.f ? v.y : (__expf(v.y) - 1.f);
            v.z = v.z > 0.f ? v.z : (__expf(v.z) - 1.f);
            v.w = v.w > 0.f ? v.w : (__expf(v.w) - 1.f);
        }
        ((float4*)(out + (size_t)node * 64))[q] = v;
    }
}

// logits[n][c] = x[n]·cW[:,c] + cb[c]
__global__ __launch_bounds__(256) void classifier_kernel(
    const float* __restrict__ x, const float* __restrict__ cw,
    const float* __restrict__ cb, float* __restrict__ out, int N)
{
    int i = blockIdx.x * blockDim.x + threadIdx.x;
    if (i >= N * 16) return;
    int n = i >> 4, c = i & 15;
    const float4* xr = (const float4*)(x + (size_t)n * 64);
    float acc = cb[c];
#pragma unroll
    for (int j4 = 0; j4 < 16; ++j4) {
        float4 xv = xr[j4];
        acc += xv.x * cw[(j4 * 4 + 0) * 16 + c];
        acc += xv.y * cw[(j4 * 4 + 1) * 16 + c];
        acc += xv.z * cw[(j4 * 4 + 2) * 16 + c];
        acc += xv.w * cw[(j4 * 4 + 3) * 16 + c];
    }
    out[i] = acc;
}

extern "C" void kernel_launch(void* const* d_in, const int* in_sizes, int n_in,
                              void* d_out, int out_size, void* d_ws, size_t ws_size,
                              hipStream_t stream)
{
    const float* X    = (const float*)d_in[0];
    const int*   adj  = (const int*)d_in[1];
    const float* W1   = (const float*)d_in[2];
    const float* a_s1 = (const float*)d_in[3];
    const float* a_d1 = (const float*)d_in[4];
    const float* b1   = (const float*)d_in[5];
    const float* W2   = (const float*)d_in[6];
    const float* a_s2 = (const float*)d_in[7];
    const float* a_d2 = (const float*)d_in[8];
    const float* b2   = (const float*)d_in[9];
    const float* cW   = (const float*)d_in[10];
    const float* cb   = (const float*)d_in[11];

    const int N  = in_sizes[0] / 128;
    const int E  = in_sizes[1] / 2;
    const int ET = E + N;
    const int NB = (N + 1023) / 1024;

    float* A       = (float*)d_ws;            // h,        N*64
    float* B       = A + (size_t)N * 64;      // layer1 x, N*64
    float* asb     = B + (size_t)N * 64;      // N
    float* adb     = asb + N;                 // N
    int*   deg     = (int*)(adb + N);         // N
    int*   cursor  = deg + N;                 // N
    int*   row_ptr = cursor + N;              // N+1
    int*   col_idx = row_ptr + (N + 1);       // E+N
    int*   bsum    = col_idx + ET;            // NB (<=1024)

    const int T = 256;
    const int nodeBlocks  = (N + T - 1) / T;
    const int edgeBlocksE = (E + T - 1) / T;
    const int edgeBlocksT = (ET + T - 1) / T;
    const int gemmBlocks  = (N + 31) / 32;
    const int aggBlocks   = (N + 3) / 4;

    // ---- CSR build (once, reused by both layers) ----
    init_deg_kernel<<<nodeBlocks, T, 0, stream>>>(deg, N);
    count_deg_kernel<<<edgeBlocksE, T, 0, stream>>>(adj, deg, E);
    scan1_kernel<<<NB, 1024, 0, stream>>>(deg, row_ptr, bsum, N);
    scan2_kernel<<<1, 1024, 0, stream>>>(bsum, NB);
    scan3_kernel<<<nodeBlocks, T, 0, stream>>>(row_ptr, cursor, deg, bsum, N);
    scatter_kernel<<<edgeBlocksT, T, 0, stream>>>(adj, cursor, col_idx, E, N);

    // ---- layer 1 ----
    gemm_alpha_kernel<128><<<gemmBlocks, T, 0, stream>>>(
        X, W1, a_s1, a_d1, A, asb, adb, N);
    gat_aggregate_kernel<<<aggBlocks, T, 0, stream>>>(
        row_ptr, col_idx, asb, adb, A, b1, B, N, 1);

    // ---- layer 2 (x written straight into d_out tail) ----
    float* out  = (float*)d_out;
    float* xout = out + (size_t)N * 16;
    gemm_alpha_kernel<64><<<gemmBlocks, T, 0, stream>>>(
        B, W2, a_s2, a_d2, A, asb, adb, N);
    gat_aggregate_kernel<<<aggBlocks, T, 0, stream>>>(
        row_ptr, col_idx, asb, adb, A, b2, xout, N, 0);

    // ---- classifier ----
    classifier_kernel<<<(N * 16 + T - 1) / T, T, 0, stream>>>(
        xout, cW, cb, out, N);
}